// Round 1
// baseline (306.190 us; speedup 1.0000x reference)
//
#include <hip/hip_runtime.h>
#include <hip/hip_bf16.h>

// Problem constants (B,T,D,F) = (4,1024,256,128)
#define BT 4096      // B*T
#define DD 256
#define FF 128
#define CAT 129

typedef __attribute__((ext_vector_type(8))) __bf16 bf16x8;
typedef __attribute__((ext_vector_type(4))) float f32x4;

__device__ __forceinline__ unsigned short f2bf(float x) {
    __bf16 b = (__bf16)x;
    return __builtin_bit_cast(unsigned short, b);
}

// ---------------------------------------------------------------------------
// k_prep: blocks 0..255 -> v1[bt][f] = b1[f] + sum_c feature[bt][c]*W1[f][1+c]
//         block 256     -> W2 cast to bf16, XOR-swizzled layout; w10 = W1[:,0]
// ---------------------------------------------------------------------------
__global__ void __launch_bounds__(256) k_prep(
    const float* __restrict__ feature, const float* __restrict__ W1,
    const float* __restrict__ b1, const float* __restrict__ W2,
    float* __restrict__ v1g, unsigned short* __restrict__ w2bf,
    float* __restrict__ w10f)
{
    __shared__ float featS[16 * 128];
    const int tid = threadIdx.x;
    const int blk = blockIdx.x;

    if (blk == 256) {
        // swizzled bf16 W2: element (g,f) stored at index (g*128+f) ^ ((g&7)<<3)
        #pragma unroll 4
        for (int i = 0; i < 64; ++i) {
            int idx = i * 256 + tid;          // 0..16383, = g*128+f
            int g = idx >> 7;
            int sidx = idx ^ ((g & 7) << 3);
            w2bf[sidx] = f2bf(W2[idx]);
        }
        if (tid < 128) w10f[tid] = W1[tid * CAT];
        return;
    }

    const int btBase = blk * 16;
    for (int i = tid; i < 16 * 128; i += 256)
        featS[i] = feature[btBase * 128 + i];
    __syncthreads();

    const int f  = tid & 127;
    const int rh = (tid >> 7) * 8;            // 0 or 8: which 8 bt-rows
    float acc[8];
    const float bb = b1[f];
    #pragma unroll
    for (int r = 0; r < 8; ++r) acc[r] = bb;

    const float* w1row = W1 + f * CAT + 1;    // stride-129 rows stay hot in L1
    for (int c = 0; c < 128; ++c) {
        const float w = w1row[c];
        #pragma unroll
        for (int r = 0; r < 8; ++r)
            acc[r] = fmaf(featS[(rh + r) * 128 + c], w, acc[r]);
    }
    #pragma unroll
    for (int r = 0; r < 8; ++r)
        v1g[(size_t)(btBase + rh + r) * 128 + f] = acc[r];
}

// ---------------------------------------------------------------------------
// k_main: one (b,t) per block. 256 threads = 4 waves (2x2 wave grid).
// Per 128-row half: h1 = prelu(w10*s + v1) -> swizzled bf16 LDS tile ->
// 64x64 wave MFMA tiles (B frags held in registers) -> fused bias/prelu/Wp/
// sigmoid epilogue.
// ---------------------------------------------------------------------------
__global__ void __launch_bounds__(256, 2) k_main(
    const float* __restrict__ inp, const float* __restrict__ b2p,
    const float* __restrict__ Wp, const float* __restrict__ bpp,
    const float* __restrict__ a1p, const float* __restrict__ a2p,
    const float* __restrict__ v1g, const unsigned short* __restrict__ w2bf,
    const float* __restrict__ w10f, float* __restrict__ out)
{
    __shared__ __align__(16) unsigned short w2s[16384];  // 32 KB
    __shared__ __align__(16) unsigned short h1s[16384];  // 32 KB (one half-tile)
    float* prs = (float*)w2s;  // 2 KB partial buffer; safe: B frags are in regs
                               // before the first write (ordered by barrier)

    const int tid  = threadIdx.x;
    const int lane = tid & 63;
    const int wv   = tid >> 6;
    const int rg   = wv >> 1, cg = wv & 1;
    const int l15  = lane & 15, l4 = lane >> 4;
    const int bt   = blockIdx.x;

    // stage pre-swizzled bf16 W2 into LDS (linear copy)
    #pragma unroll
    for (int i = 0; i < 8; ++i)
        ((int4*)w2s)[i * 256 + tid] = ((const int4*)w2bf)[i * 256 + tid];

    const float a1   = a1p[0], a2v = a2p[0];
    const float wpi0 = Wp[128], wpi1 = Wp[CAT + 128];
    const float bp0  = bpp[0],  bp1  = bpp[1];
    __syncthreads();

    // B fragments (W2^T): lane holds col g = cg*64+nt*16+l15, k-window f.
    // Read = W2 row g, 8 consecutive f -> contiguous; swizzle kills conflicts.
    bf16x8 bfr[4][4];
    float b2r[4], wpa[4], wpb[4];
    #pragma unroll
    for (int nt = 0; nt < 4; ++nt) {
        const int g = cg * 64 + nt * 16 + l15;
        b2r[nt] = b2p[g];
        wpa[nt] = Wp[g];
        wpb[nt] = Wp[CAT + g];
        #pragma unroll
        for (int kc = 0; kc < 4; ++kc) {
            const int fc  = kc * 32 + l4 * 8;
            const int idx = (g * 128 + fc) ^ ((g & 7) << 3);
            bfr[nt][kc] = *(const bf16x8*)&w2s[idx];
        }
    }

    const float*  inpRow = inp + (size_t)bt * DD;
    const float4* v1v    = (const float4*)(v1g + (size_t)bt * 128);
    const float4* w1v    = (const float4*)w10f;
    const f32x4 fzero = {0.f, 0.f, 0.f, 0.f};

    for (int half = 0; half < 2; ++half) {
        // ---- h1 half-tile: 128 rows x 128 f, 2 threads per row ----
        {
            const int lr = tid >> 1;
            const int fb = (tid & 1) << 6;
            const float s = inpRow[half * 128 + lr];
            #pragma unroll
            for (int f8 = 0; f8 < 8; ++f8) {
                const int q = (fb >> 2) + f8 * 2;
                const float4 va0 = v1v[q], va1 = v1v[q + 1];
                const float4 wa0 = w1v[q], wa1 = w1v[q + 1];
                const float va[8] = {va0.x, va0.y, va0.z, va0.w,
                                     va1.x, va1.y, va1.z, va1.w};
                const float wa[8] = {wa0.x, wa0.y, wa0.z, wa0.w,
                                     wa1.x, wa1.y, wa1.z, wa1.w};
                bf16x8 hv;
                #pragma unroll
                for (int j = 0; j < 8; ++j) {
                    float h = fmaf(wa[j], s, va[j]);
                    h = fmaxf(h, 0.f) + a1 * fminf(h, 0.f);   // prelu
                    hv[j] = (__bf16)h;
                }
                const int idx = (lr * 128 + fb + f8 * 8) ^ ((lr & 7) << 3);
                *(bf16x8*)&h1s[idx] = hv;
            }
        }
        __syncthreads();

        // ---- GEMM: wave tile 64 rows x 64 cols, 4x4 fragment blocking ----
        f32x4 acc[4][4];
        #pragma unroll
        for (int rt = 0; rt < 4; ++rt)
            #pragma unroll
            for (int nt = 0; nt < 4; ++nt) acc[rt][nt] = fzero;

        #pragma unroll
        for (int kc = 0; kc < 4; ++kc) {
            bf16x8 afr[4];
            #pragma unroll
            for (int rt = 0; rt < 4; ++rt) {
                const int lr  = rg * 64 + rt * 16 + l15;
                const int fc  = kc * 32 + l4 * 8;
                const int idx = (lr * 128 + fc) ^ ((lr & 7) << 3);
                afr[rt] = *(const bf16x8*)&h1s[idx];
            }
            #pragma unroll
            for (int rt = 0; rt < 4; ++rt)
                #pragma unroll
                for (int nt = 0; nt < 4; ++nt)
                    acc[rt][nt] = __builtin_amdgcn_mfma_f32_16x16x32_bf16(
                        afr[rt], bfr[nt][kc], acc[rt][nt], 0, 0, 0);
        }

        // ---- epilogue: + b2, prelu(a2), Wp partial dots in-register ----
        float pp0[4][4], pp1[4][4];
        #pragma unroll
        for (int rt = 0; rt < 4; ++rt)
            #pragma unroll
            for (int j = 0; j < 4; ++j) { pp0[rt][j] = 0.f; pp1[rt][j] = 0.f; }

        #pragma unroll
        for (int rt = 0; rt < 4; ++rt)
            #pragma unroll
            for (int nt = 0; nt < 4; ++nt)
                #pragma unroll
                for (int j = 0; j < 4; ++j) {
                    float h2 = acc[rt][nt][j] + b2r[nt];
                    h2 = fmaxf(h2, 0.f) + a2v * fminf(h2, 0.f);
                    pp0[rt][j] = fmaf(wpa[nt], h2, pp0[rt][j]);
                    pp1[rt][j] = fmaf(wpb[nt], h2, pp1[rt][j]);
                }

        // reduce across the 16 lanes holding one row's 64 cols
        #pragma unroll
        for (int rt = 0; rt < 4; ++rt)
            #pragma unroll
            for (int j = 0; j < 4; ++j) {
                float s0 = pp0[rt][j], s1 = pp1[rt][j];
                s0 += __shfl_xor(s0, 1);  s1 += __shfl_xor(s1, 1);
                s0 += __shfl_xor(s0, 2);  s1 += __shfl_xor(s1, 2);
                s0 += __shfl_xor(s0, 4);  s1 += __shfl_xor(s1, 4);
                s0 += __shfl_xor(s0, 8);  s1 += __shfl_xor(s1, 8);
                if (l15 == 0) {
                    const int lr = rg * 64 + rt * 16 + l4 * 4 + j;
                    prs[(cg * 128 + lr) * 2 + 0] = s0;
                    prs[(cg * 128 + lr) * 2 + 1] = s1;
                }
            }
        __syncthreads();

        // ---- final: combine col-halves, + Wp[:,128]*s + bp, gate, store ----
        if (tid < 128) {
            const float s  = inpRow[half * 128 + tid];
            const float p0 = prs[tid * 2]     + prs[(128 + tid) * 2]
                           + wpi0 * s + bp0;
            const float p1 = prs[tid * 2 + 1] + prs[(128 + tid) * 2 + 1]
                           + wpi1 * s + bp1;
            const float gg = p0 / (1.f + __expf(-p1));      // p0 * sigmoid(p1)
            out[(size_t)bt * DD + half * 128 + tid] = s * (1.f + gg);
        }
        __syncthreads();  // protect h1s/prs reuse in next half
    }
}

// ---------------------------------------------------------------------------
extern "C" void kernel_launch(void* const* d_in, const int* in_sizes, int n_in,
                              void* d_out, int out_size, void* d_ws, size_t ws_size,
                              hipStream_t stream)
{
    (void)in_sizes; (void)n_in; (void)out_size; (void)ws_size;
    const float* input   = (const float*)d_in[0];
    const float* feature = (const float*)d_in[1];
    // d_in[2] slider: unused by the reference computation
    const float* W1 = (const float*)d_in[3];
    const float* b1 = (const float*)d_in[4];
    const float* a1 = (const float*)d_in[5];
    const float* W2 = (const float*)d_in[6];
    const float* b2 = (const float*)d_in[7];
    const float* a2 = (const float*)d_in[8];
    const float* Wp = (const float*)d_in[9];
    const float* bp = (const float*)d_in[10];
    float* out = (float*)d_out;

    // workspace layout (needs ~2.03 MB):
    float*          v1g  = (float*)d_ws;                                  // 2 MB
    unsigned short* w2bf = (unsigned short*)((char*)d_ws + (size_t)BT * 128 * 4);
    float*          w10f = (float*)((char*)d_ws + (size_t)BT * 128 * 4 + 16384 * 2);

    k_prep<<<dim3(257), dim3(256), 0, stream>>>(feature, W1, b1, W2,
                                                v1g, w2bf, w10f);
    k_main<<<dim3(BT), dim3(256), 0, stream>>>(input, b2, Wp, bp, a1, a2,
                                               v1g, w2bf, w10f, out);
}

// Round 2
// 125.018 us; speedup vs baseline: 2.4492x; 2.4492x over previous
//
#include <hip/hip_runtime.h>
#include <hip/hip_bf16.h>

// Problem constants (B,T,D,F) = (4,1024,256,128)
#define BT 4096
#define DD 256
#define CAT 129
#define GRID_MAIN 768

typedef __attribute__((ext_vector_type(8))) __bf16 bf16x8;
typedef __attribute__((ext_vector_type(4))) float f32x4;

static __device__ __forceinline__ unsigned short f2bf(float x) {
    __bf16 b = (__bf16)x;
    return __builtin_bit_cast(unsigned short, b);
}
static __device__ __forceinline__ __bf16 tobf(float x) { return (__bf16)x; }

// ---------------------------------------------------------------------------
// k_cvt: cast W2 and W1[:,1:] to bf16 with XOR-swizzled layout; copy W1[:,0].
// ---------------------------------------------------------------------------
__global__ void __launch_bounds__(256) k_cvt(
    const float* __restrict__ W1, const float* __restrict__ W2,
    unsigned short* __restrict__ w2bf, unsigned short* __restrict__ w1bf,
    float* __restrict__ w10f)
{
    const int t = threadIdx.x, b = blockIdx.x;
    if (b < 4) {
        #pragma unroll
        for (int i = 0; i < 16; ++i) {
            int idx = b * 4096 + i * 256 + t;       // g*128+f
            int g = idx >> 7;
            w2bf[idx ^ ((g & 7) << 3)] = f2bf(W2[idx]);
        }
    } else {
        int q = b - 4;
        #pragma unroll
        for (int i = 0; i < 16; ++i) {
            int idx = q * 4096 + i * 256 + t;       // f*128+c
            int f = idx >> 7, c = idx & 127;
            w1bf[idx ^ ((f & 7) << 3)] = f2bf(W1[f * CAT + 1 + c]);
        }
        if (q == 0 && t < 128) w10f[t] = W1[t * CAT];
    }
}

// ---------------------------------------------------------------------------
// k_prep2: v1[bt][f] = b1[f] + feature[bt] @ W1[:,1:]^T  as a bf16 MFMA GEMM.
// 32 bt-rows per block; D[f,r] via swapped operands mfma(W1frag, featfrag).
// ---------------------------------------------------------------------------
__global__ void __launch_bounds__(256) k_prep2(
    const float* __restrict__ feature, const unsigned short* __restrict__ w1bf,
    const float* __restrict__ b1p, float* __restrict__ v1g)
{
    __shared__ __align__(16) unsigned short fS[4096];   // 32 x 128 bf16, swizzled
    const int t = threadIdx.x;
    const int r0 = blockIdx.x * 32;

    #pragma unroll
    for (int ch = 0; ch < 2; ++ch) {
        int e = ch * 2048 + t * 8;
        int r = e >> 7, c = e & 127;
        const float4* src = (const float4*)(feature + (size_t)(r0 + r) * 128 + c);
        float4 x0 = src[0], x1 = src[1];
        bf16x8 hv;
        hv[0]=tobf(x0.x); hv[1]=tobf(x0.y); hv[2]=tobf(x0.z); hv[3]=tobf(x0.w);
        hv[4]=tobf(x1.x); hv[5]=tobf(x1.y); hv[6]=tobf(x1.z); hv[7]=tobf(x1.w);
        *(bf16x8*)&fS[e ^ ((r & 7) << 3)] = hv;
    }
    __syncthreads();

    const int lane = t & 63, wv = t >> 6;
    const int l15 = lane & 15, l4 = lane >> 4;

    bf16x8 bfr[2][4];
    float4 b1v[2];
    #pragma unroll
    for (int nt = 0; nt < 2; ++nt) {
        const int f0 = wv * 32 + nt * 16;
        b1v[nt] = *(const float4*)(b1p + f0 + l4 * 4);
        #pragma unroll
        for (int kc = 0; kc < 4; ++kc) {
            int f = f0 + l15, c = kc * 32 + l4 * 8;
            bfr[nt][kc] = *(const bf16x8*)&w1bf[(f * 128 + c) ^ ((f & 7) << 3)];
        }
    }

    const f32x4 fz = {0.f, 0.f, 0.f, 0.f};
    f32x4 acc[2][2] = {{fz, fz}, {fz, fz}};
    #pragma unroll
    for (int kc = 0; kc < 4; ++kc) {
        bf16x8 afr[2];
        #pragma unroll
        for (int rt = 0; rt < 2; ++rt) {
            int r = rt * 16 + l15, c = kc * 32 + l4 * 8;
            afr[rt] = *(const bf16x8*)&fS[(r * 128 + c) ^ ((r & 7) << 3)];
        }
        #pragma unroll
        for (int nt = 0; nt < 2; ++nt)
            #pragma unroll
            for (int rt = 0; rt < 2; ++rt)
                acc[nt][rt] = __builtin_amdgcn_mfma_f32_16x16x32_bf16(
                    bfr[nt][kc], afr[rt], acc[nt][rt], 0, 0, 0);
    }

    #pragma unroll
    for (int nt = 0; nt < 2; ++nt)
        #pragma unroll
        for (int rt = 0; rt < 2; ++rt) {
            float4 o;
            o.x = acc[nt][rt][0] + b1v[nt].x;
            o.y = acc[nt][rt][1] + b1v[nt].y;
            o.z = acc[nt][rt][2] + b1v[nt].z;
            o.w = acc[nt][rt][3] + b1v[nt].w;
            *(float4*)(v1g + (size_t)(r0 + rt * 16 + l15) * 128
                           + wv * 32 + nt * 16 + l4 * 4) = o;
        }
}

// ---------------------------------------------------------------------------
// k_main: persistent blocks, grid-stride over bt. Wave wv owns g-block
// [wv*32, wv*32+32); per 64-row quarter: h1 -> swizzled bf16 LDS ->
// D[g,r] = mfma(W2frag, h1frag) -> epilogue with 2-step shfl reduce.
// ---------------------------------------------------------------------------
__global__ void __launch_bounds__(256, 3) k_main(
    const float* __restrict__ inp, const float* __restrict__ b2p,
    const float* __restrict__ Wp, const float* __restrict__ bpp,
    const float* __restrict__ a1p, const float* __restrict__ a2p,
    const float* __restrict__ v1g, const unsigned short* __restrict__ w2bf,
    const float* __restrict__ w10f, float* __restrict__ out)
{
    __shared__ __align__(16) unsigned short w2s[16384];  // 32 KB
    __shared__ __align__(16) unsigned short h1s[8192];   // 16 KB (64-row tile)
    __shared__ float2 prs[256];                          // [wv][r] partials, 2 KB

    const int tid  = threadIdx.x;
    const int lane = tid & 63, wv = tid >> 6;
    const int l15  = lane & 15, l4 = lane >> 4;

    // stage pre-swizzled bf16 W2 into LDS once per block
    #pragma unroll
    for (int i = 0; i < 8; ++i)
        ((int4*)w2s)[i * 256 + tid] = ((const int4*)w2bf)[i * 256 + tid];

    const float a1   = a1p[0], a2v = a2p[0];
    const float wpi0 = Wp[128], wpi1 = Wp[CAT + 128];
    const float bp0  = bpp[0],  bp1  = bpp[1];
    __syncthreads();

    // per-wave constants: W2 B-frags (held in regs), b2/Wp slices
    bf16x8 bfr[2][4];
    float4 b2v[2], wpav[2], wpbv[2];
    #pragma unroll
    for (int nt = 0; nt < 2; ++nt) {
        const int g0 = wv * 32 + nt * 16;
        b2v[nt]  = *(const float4*)(b2p + g0 + l4 * 4);
        wpav[nt] = *(const float4*)(Wp  + g0 + l4 * 4);
        #pragma unroll
        for (int j = 0; j < 4; ++j)
            ((float*)&wpbv[nt])[j] = Wp[CAT + g0 + l4 * 4 + j];
        #pragma unroll
        for (int kc = 0; kc < 4; ++kc) {
            const int g = g0 + l15, f = kc * 32 + l4 * 8;
            bfr[nt][kc] = *(const bf16x8*)&w2s[(g * 128 + f) ^ ((g & 7) << 3)];
        }
    }

    const f32x4 fz = {0.f, 0.f, 0.f, 0.f};

    for (int bt = blockIdx.x; bt < BT; bt += GRID_MAIN) {
        const float*  inpRow = inp + (size_t)bt * DD;
        const float4* v1v    = (const float4*)(v1g + (size_t)bt * 128);
        const float4* w1v    = (const float4*)w10f;

        for (int qt = 0; qt < 4; ++qt) {
            // ---- h1 tile: 64 rows x 128 f; 4 threads per row ----
            {
                const int lr = tid >> 2;
                const int fb = (tid & 3) << 5;
                const float s = inpRow[qt * 64 + lr];
                #pragma unroll
                for (int f8 = 0; f8 < 4; ++f8) {
                    const int qq = (fb >> 2) + f8 * 2;
                    const float4 va0 = v1v[qq], va1 = v1v[qq + 1];
                    const float4 wa0 = w1v[qq], wa1 = w1v[qq + 1];
                    const float va[8] = {va0.x, va0.y, va0.z, va0.w,
                                         va1.x, va1.y, va1.z, va1.w};
                    const float wa[8] = {wa0.x, wa0.y, wa0.z, wa0.w,
                                         wa1.x, wa1.y, wa1.z, wa1.w};
                    bf16x8 hv;
                    #pragma unroll
                    for (int j = 0; j < 8; ++j) {
                        float h = fmaf(wa[j], s, va[j]);
                        h = fmaxf(h, 0.f) + a1 * fminf(h, 0.f);
                        hv[j] = (__bf16)h;
                    }
                    const int idx = (lr * 128 + fb + f8 * 8) ^ ((lr & 7) << 3);
                    *(bf16x8*)&h1s[idx] = hv;
                }
            }
            __syncthreads();

            // ---- MFMA: D[g,r], g = wave's 32-block, r = all 64 rows ----
            f32x4 acc[2][4];
            #pragma unroll
            for (int nt = 0; nt < 2; ++nt)
                #pragma unroll
                for (int rt = 0; rt < 4; ++rt) acc[nt][rt] = fz;

            #pragma unroll
            for (int kc = 0; kc < 4; ++kc) {
                bf16x8 afr[4];
                #pragma unroll
                for (int rt = 0; rt < 4; ++rt) {
                    const int r = rt * 16 + l15, f = kc * 32 + l4 * 8;
                    afr[rt] = *(const bf16x8*)&h1s[(r * 128 + f) ^ ((r & 7) << 3)];
                }
                #pragma unroll
                for (int nt = 0; nt < 2; ++nt)
                    #pragma unroll
                    for (int rt = 0; rt < 4; ++rt)
                        acc[nt][rt] = __builtin_amdgcn_mfma_f32_16x16x32_bf16(
                            bfr[nt][kc], afr[rt], acc[nt][rt], 0, 0, 0);
            }

            // ---- epilogue: b2 + prelu(a2) + Wp dots; reduce over l4 ----
            #pragma unroll
            for (int rt = 0; rt < 4; ++rt) {
                float s0 = 0.f, s1 = 0.f;
                #pragma unroll
                for (int nt = 0; nt < 2; ++nt)
                    #pragma unroll
                    for (int j = 0; j < 4; ++j) {
                        float h2 = acc[nt][rt][j] + ((const float*)&b2v[nt])[j];
                        h2 = fmaxf(h2, 0.f) + a2v * fminf(h2, 0.f);
                        s0 = fmaf(((const float*)&wpav[nt])[j], h2, s0);
                        s1 = fmaf(((const float*)&wpbv[nt])[j], h2, s1);
                    }
                s0 += __shfl_xor(s0, 16); s0 += __shfl_xor(s0, 32);
                s1 += __shfl_xor(s1, 16); s1 += __shfl_xor(s1, 32);
                if (l4 == 0) {
                    float2 v; v.x = s0; v.y = s1;
                    prs[wv * 64 + rt * 16 + l15] = v;
                }
            }
            __syncthreads();

            // ---- final: combine 4 g-blocks, gate, store ----
            if (tid < 64) {
                const float s = inpRow[qt * 64 + tid];
                const float2 p0 = prs[tid], p1 = prs[64 + tid];
                const float2 p2 = prs[128 + tid], p3 = prs[192 + tid];
                const float e0 = p0.x + p1.x + p2.x + p3.x + wpi0 * s + bp0;
                const float e1 = p0.y + p1.y + p2.y + p3.y + wpi1 * s + bp1;
                const float gg = e0 / (1.f + __expf(-e1));
                out[(size_t)bt * DD + qt * 64 + tid] = s * (1.f + gg);
            }
            __syncthreads();
        }
    }
}

// ---------------------------------------------------------------------------
extern "C" void kernel_launch(void* const* d_in, const int* in_sizes, int n_in,
                              void* d_out, int out_size, void* d_ws, size_t ws_size,
                              hipStream_t stream)
{
    (void)in_sizes; (void)n_in; (void)out_size; (void)ws_size;
    const float* input   = (const float*)d_in[0];
    const float* feature = (const float*)d_in[1];
    // d_in[2] slider: unused by the reference computation
    const float* W1 = (const float*)d_in[3];
    const float* b1 = (const float*)d_in[4];
    const float* a1 = (const float*)d_in[5];
    const float* W2 = (const float*)d_in[6];
    const float* b2 = (const float*)d_in[7];
    const float* a2 = (const float*)d_in[8];
    const float* Wp = (const float*)d_in[9];
    const float* bp = (const float*)d_in[10];
    float* out = (float*)d_out;

    // workspace: v1g 2MB | w2bf 32KB | w1bf 32KB | w10f 512B
    float*          v1g  = (float*)d_ws;
    unsigned short* w2bf = (unsigned short*)((char*)d_ws + (size_t)BT * 128 * 4);
    unsigned short* w1bf = w2bf + 16384;
    float*          w10f = (float*)(w1bf + 16384);

    k_cvt  <<<dim3(8),         dim3(256), 0, stream>>>(W1, W2, w2bf, w1bf, w10f);
    k_prep2<<<dim3(128),       dim3(256), 0, stream>>>(feature, w1bf, b1, v1g);
    k_main <<<dim3(GRID_MAIN), dim3(256), 0, stream>>>(input, b2, Wp, bp, a1, a2,
                                                       v1g, w2bf, w10f, out);
}

// Round 3
// 76.974 us; speedup vs baseline: 3.9778x; 1.6242x over previous
//
#include <hip/hip_runtime.h>
#include <hip/hip_bf16.h>

// Problem constants (B,T,D,F) = (4,1024,256,128)
#define BT 4096
#define DD 256
#define CAT 129

typedef __attribute__((ext_vector_type(8))) __bf16 bf16x8;
typedef __attribute__((ext_vector_type(4))) float f32x4;

static __device__ __forceinline__ unsigned short f2bf(float x) {
    __bf16 b = (__bf16)x;
    return __builtin_bit_cast(unsigned short, b);
}
static __device__ __forceinline__ __bf16 tobf(float x) { return (__bf16)x; }

// ---------------------------------------------------------------------------
// k_cvt: blocks 0..7: W2 -> bf16 XOR-swizzled. blocks 8..15: W1[:,1:] -> bf16
// swizzled; block 8 also copies W1[:,0].
// ---------------------------------------------------------------------------
__global__ void __launch_bounds__(256) k_cvt(
    const float* __restrict__ W1, const float* __restrict__ W2,
    unsigned short* __restrict__ w2bf, unsigned short* __restrict__ w1bf,
    float* __restrict__ w10f)
{
    const int t = threadIdx.x, b = blockIdx.x;
    if (b < 8) {
        #pragma unroll
        for (int i = 0; i < 8; ++i) {
            int idx = b * 2048 + i * 256 + t;       // g*128+f
            int g = idx >> 7;
            w2bf[idx ^ ((g & 7) << 3)] = f2bf(W2[idx]);
        }
    } else {
        int q = b - 8;
        #pragma unroll
        for (int i = 0; i < 8; ++i) {
            int idx = q * 2048 + i * 256 + t;       // f*128+c
            int f = idx >> 7, c = idx & 127;
            w1bf[idx ^ ((f & 7) << 3)] = f2bf(W1[f * CAT + 1 + c]);
        }
        if (q == 0 && t < 128) w10f[t] = W1[t * CAT];
    }
}

// ---------------------------------------------------------------------------
// k_prep2: v1 = b1 + feature @ W1[:,1:]^T  (bf16 MFMA GEMM, 16 rows/block).
// ---------------------------------------------------------------------------
__global__ void __launch_bounds__(256) k_prep2(
    const float* __restrict__ feature, const unsigned short* __restrict__ w1bf,
    const float* __restrict__ b1p, float* __restrict__ v1g)
{
    __shared__ __align__(16) unsigned short fS[2048];   // 16 x 128 bf16, swizzled
    const int t = threadIdx.x;
    const int r0 = blockIdx.x * 16;

    {
        int e = t * 8;
        int r = e >> 7, c = e & 127;
        const float4* src = (const float4*)(feature + (size_t)(r0 + r) * 128 + c);
        float4 x0 = src[0], x1 = src[1];
        bf16x8 hv;
        hv[0]=tobf(x0.x); hv[1]=tobf(x0.y); hv[2]=tobf(x0.z); hv[3]=tobf(x0.w);
        hv[4]=tobf(x1.x); hv[5]=tobf(x1.y); hv[6]=tobf(x1.z); hv[7]=tobf(x1.w);
        *(bf16x8*)&fS[e ^ ((r & 7) << 3)] = hv;
    }
    __syncthreads();

    const int lane = t & 63, wv = t >> 6;
    const int l15 = lane & 15, l4 = lane >> 4;

    bf16x8 bfr[2][4];
    float4 b1v[2];
    #pragma unroll
    for (int nt = 0; nt < 2; ++nt) {
        const int f0 = wv * 32 + nt * 16;
        b1v[nt] = *(const float4*)(b1p + f0 + l4 * 4);
        #pragma unroll
        for (int kc = 0; kc < 4; ++kc) {
            int f = f0 + l15, c = kc * 32 + l4 * 8;
            bfr[nt][kc] = *(const bf16x8*)&w1bf[(f * 128 + c) ^ ((f & 7) << 3)];
        }
    }

    const f32x4 fz = {0.f, 0.f, 0.f, 0.f};
    f32x4 acc[2] = {fz, fz};
    #pragma unroll
    for (int kc = 0; kc < 4; ++kc) {
        bf16x8 afr;
        {
            int r = l15, c = kc * 32 + l4 * 8;
            afr = *(const bf16x8*)&fS[(r * 128 + c) ^ ((r & 7) << 3)];
        }
        #pragma unroll
        for (int nt = 0; nt < 2; ++nt)
            acc[nt] = __builtin_amdgcn_mfma_f32_16x16x32_bf16(
                bfr[nt][kc], afr, acc[nt], 0, 0, 0);
    }

    #pragma unroll
    for (int nt = 0; nt < 2; ++nt) {
        float4 o;
        o.x = acc[nt][0] + ((const float*)&b1v[nt])[0];
        o.y = acc[nt][1] + ((const float*)&b1v[nt])[1];
        o.z = acc[nt][2] + ((const float*)&b1v[nt])[2];
        o.w = acc[nt][3] + ((const float*)&b1v[nt])[3];
        *(float4*)(v1g + (size_t)(r0 + l15) * 128 + wv * 32 + nt * 16 + l4 * 4) = o;
    }
}

// ---------------------------------------------------------------------------
// k_main: one bt per block, 512 threads = 8 waves (2 row-groups x 4 col-
// groups). Per-bt operands (inp/v1/w10/b2/Wp rows) staged in LDS once;
// W2 B-frags in registers loaded straight from global. Per 64-row quarter:
// h1 (LDS-broadcast reads) -> swizzled bf16 LDS -> MFMA D[g,r] -> fused
// epilogue; double-buffered prs gives 2 barriers/quarter, store overlaps.
// ---------------------------------------------------------------------------
__global__ void __launch_bounds__(512, 4) k_main(
    const float* __restrict__ inp, const float* __restrict__ b2p,
    const float* __restrict__ Wp, const float* __restrict__ bpp,
    const float* __restrict__ a1p, const float* __restrict__ a2p,
    const float* __restrict__ v1g, const unsigned short* __restrict__ w2bf,
    const float* __restrict__ w10f, float* __restrict__ out)
{
    __shared__ __align__(16) unsigned short h1s[8192];  // 16 KB, 64x128 swizzled
    __shared__ float v1s[8][20];                        // bank-padded broadcast
    __shared__ float w10s[8][20];
    __shared__ float inps[256];
    __shared__ float b2s[128], wpas[128], wpbs[128];
    __shared__ float2 prs[2][4][64];                    // double-buffered

    const int tid  = threadIdx.x;
    const int lane = tid & 63, wv = tid >> 6;
    const int rg   = wv >> 2, cg = wv & 3;
    const int l15  = lane & 15, l4 = lane >> 4;
    const int bt   = blockIdx.x;

    const float* inpRow = inp + (size_t)bt * DD;
    const float* v1row  = v1g + (size_t)bt * 128;

    // ---- stage per-bt rows + shared vectors into LDS (once) ----
    if (tid < 256)      inps[tid] = inpRow[tid];
    else if (tid < 384) b2s[tid - 256] = b2p[tid - 256];
    else                wpas[tid - 384] = Wp[tid - 384];
    if (tid < 128)      wpbs[tid] = Wp[CAT + tid];
    else if (tid < 256) { int f = tid - 128; v1s[f >> 4][f & 15]  = v1row[f]; }
    else if (tid < 384) { int f = tid - 256; w10s[f >> 4][f & 15] = w10f[f]; }

    // ---- W2 B-frags straight from global (L2/L1-hot, pre-swizzled) ----
    bf16x8 bfr[2][4];
    #pragma unroll
    for (int nt = 0; nt < 2; ++nt) {
        const int g = cg * 32 + nt * 16 + l15;
        #pragma unroll
        for (int kc = 0; kc < 4; ++kc) {
            const int f = kc * 32 + l4 * 8;
            bfr[nt][kc] = *(const bf16x8*)&w2bf[(g * 128 + f) ^ ((g & 7) << 3)];
        }
    }

    const float a1   = a1p[0], a2v = a2p[0];
    const float wpi0 = Wp[128], wpi1 = Wp[CAT + 128];
    const float bp0  = bpp[0],  bp1  = bpp[1];
    __syncthreads();

    const int lr = tid >> 3;        // h1-gen row 0..63
    const int fg = tid & 7;         // h1-gen 16-f group
    const f32x4 fz = {0.f, 0.f, 0.f, 0.f};

    for (int qt = 0; qt < 4; ++qt) {
        float2* prsC = &prs[qt & 1][0][0];

        // ---- h1 tile: 64 rows x 128 f, reads broadcast from LDS ----
        {
            const float s = inps[qt * 64 + lr];
            #pragma unroll
            for (int f8 = 0; f8 < 2; ++f8) {
                const float4 va0 = *(const float4*)&v1s[fg][f8 * 8];
                const float4 va1 = *(const float4*)&v1s[fg][f8 * 8 + 4];
                const float4 wa0 = *(const float4*)&w10s[fg][f8 * 8];
                const float4 wa1 = *(const float4*)&w10s[fg][f8 * 8 + 4];
                const float va[8] = {va0.x, va0.y, va0.z, va0.w,
                                     va1.x, va1.y, va1.z, va1.w};
                const float wa[8] = {wa0.x, wa0.y, wa0.z, wa0.w,
                                     wa1.x, wa1.y, wa1.z, wa1.w};
                bf16x8 hv;
                #pragma unroll
                for (int j = 0; j < 8; ++j) {
                    float h = fmaf(wa[j], s, va[j]);
                    h = fmaxf(h, 0.f) + a1 * fminf(h, 0.f);
                    hv[j] = (__bf16)h;
                }
                const int idx = (lr * 128 + fg * 16 + f8 * 8) ^ ((lr & 7) << 3);
                *(bf16x8*)&h1s[idx] = hv;
            }
        }
        __syncthreads();

        // ---- MFMA: wave = 32 rows (rg) x 32 cols (cg), D[g,r] ----
        f32x4 acc[2][2] = {{fz, fz}, {fz, fz}};
        #pragma unroll
        for (int kc = 0; kc < 4; ++kc) {
            bf16x8 afr[2];
            #pragma unroll
            for (int rt = 0; rt < 2; ++rt) {
                const int r = rg * 32 + rt * 16 + l15;
                const int f = kc * 32 + l4 * 8;
                afr[rt] = *(const bf16x8*)&h1s[(r * 128 + f) ^ ((r & 7) << 3)];
            }
            #pragma unroll
            for (int nt = 0; nt < 2; ++nt)
                #pragma unroll
                for (int rt = 0; rt < 2; ++rt)
                    acc[nt][rt] = __builtin_amdgcn_mfma_f32_16x16x32_bf16(
                        bfr[nt][kc], afr[rt], acc[nt][rt], 0, 0, 0);
        }

        // ---- epilogue: b2 + prelu(a2) + Wp partial dots, reduce over l4 ----
        float4 b2q[2], wq0[2], wq1[2];
        #pragma unroll
        for (int nt = 0; nt < 2; ++nt) {
            b2q[nt] = *(const float4*)&b2s[cg * 32 + nt * 16 + l4 * 4];
            wq0[nt] = *(const float4*)&wpas[cg * 32 + nt * 16 + l4 * 4];
            wq1[nt] = *(const float4*)&wpbs[cg * 32 + nt * 16 + l4 * 4];
        }
        #pragma unroll
        for (int rt = 0; rt < 2; ++rt) {
            float s0 = 0.f, s1 = 0.f;
            #pragma unroll
            for (int nt = 0; nt < 2; ++nt)
                #pragma unroll
                for (int j = 0; j < 4; ++j) {
                    float h2 = acc[nt][rt][j] + ((const float*)&b2q[nt])[j];
                    h2 = fmaxf(h2, 0.f) + a2v * fminf(h2, 0.f);
                    s0 = fmaf(((const float*)&wq0[nt])[j], h2, s0);
                    s1 = fmaf(((const float*)&wq1[nt])[j], h2, s1);
                }
            s0 += __shfl_xor(s0, 16); s0 += __shfl_xor(s0, 32);
            s1 += __shfl_xor(s1, 16); s1 += __shfl_xor(s1, 32);
            if (l4 == 0) {
                float2 v; v.x = s0; v.y = s1;
                prsC[cg * 64 + rg * 32 + rt * 16 + l15] = v;
            }
        }
        __syncthreads();

        // ---- final: wave 0 combines 4 col-groups + gates + stores,
        //      other waves run ahead into next quarter's h1-gen ----
        if (wv == 0) {
            const float s = inps[qt * 64 + lane];
            const float2 q0 = prsC[lane],       q1 = prsC[64 + lane];
            const float2 q2 = prsC[128 + lane], q3 = prsC[192 + lane];
            const float e0 = q0.x + q1.x + q2.x + q3.x + wpi0 * s + bp0;
            const float e1 = q0.y + q1.y + q2.y + q3.y + wpi1 * s + bp1;
            const float gg = e0 / (1.f + __expf(-e1));
            out[(size_t)bt * DD + qt * 64 + lane] = s * (1.f + gg);
        }
    }
}

// ---------------------------------------------------------------------------
extern "C" void kernel_launch(void* const* d_in, const int* in_sizes, int n_in,
                              void* d_out, int out_size, void* d_ws, size_t ws_size,
                              hipStream_t stream)
{
    (void)in_sizes; (void)n_in; (void)out_size; (void)ws_size;
    const float* input   = (const float*)d_in[0];
    const float* feature = (const float*)d_in[1];
    // d_in[2] slider: unused by the reference computation
    const float* W1 = (const float*)d_in[3];
    const float* b1 = (const float*)d_in[4];
    const float* a1 = (const float*)d_in[5];
    const float* W2 = (const float*)d_in[6];
    const float* b2 = (const float*)d_in[7];
    const float* a2 = (const float*)d_in[8];
    const float* Wp = (const float*)d_in[9];
    const float* bp = (const float*)d_in[10];
    float* out = (float*)d_out;

    // workspace: v1g 2MB | w2bf 32KB | w1bf 32KB | w10f 512B
    float*          v1g  = (float*)d_ws;
    unsigned short* w2bf = (unsigned short*)((char*)d_ws + (size_t)BT * 128 * 4);
    unsigned short* w1bf = w2bf + 16384;
    float*          w10f = (float*)(w1bf + 16384);

    k_cvt  <<<dim3(16),  dim3(256), 0, stream>>>(W1, W2, w2bf, w1bf, w10f);
    k_prep2<<<dim3(256), dim3(256), 0, stream>>>(feature, w1bf, b1, v1g);
    k_main <<<dim3(BT),  dim3(512), 0, stream>>>(input, b2, Wp, bp, a1, a2,
                                                 v1g, w2bf, w10f, out);
}

// Round 5
// 63.765 us; speedup vs baseline: 4.8019x; 1.2072x over previous
//
#include <hip/hip_runtime.h>
#include <hip/hip_bf16.h>

// Problem constants (B,T,D,F) = (4,1024,256,128)
#define BT 4096
#define DD 256
#define CAT 129

typedef __attribute__((ext_vector_type(8))) _Float16 f16x8;
typedef __attribute__((ext_vector_type(4))) _Float16 f16x4;
typedef __attribute__((ext_vector_type(2))) _Float16 h2;
typedef __attribute__((ext_vector_type(4))) float f32x4;

static __device__ __forceinline__ h2 cvt_pk(float a, float b) {
    return __builtin_bit_cast(h2, __builtin_amdgcn_cvt_pkrtz(a, b));
}

static __device__ __forceinline__ float fdot2f(h2 a, h2 b, float c) {
#if __has_builtin(__builtin_amdgcn_fdot2)
    return __builtin_amdgcn_fdot2(__builtin_bit_cast(__fp16 __attribute__((ext_vector_type(2))), a),
                                  __builtin_bit_cast(__fp16 __attribute__((ext_vector_type(2))), b),
                                  c, false);
#else
    return fmaf((float)a[0], (float)b[0], fmaf((float)a[1], (float)b[1], c));
#endif
}

// ---------------------------------------------------------------------------
// k_cvt: blocks 0..7: W2 -> f16 XOR-swizzled. blocks 8..15: W1[:,1:] -> f16
// swizzled; block 8 also converts W1[:,0] -> w10h.
// ---------------------------------------------------------------------------
__global__ void __launch_bounds__(256) k_cvt(
    const float* __restrict__ W1, const float* __restrict__ W2,
    _Float16* __restrict__ w2h, _Float16* __restrict__ w1h,
    _Float16* __restrict__ w10h)
{
    const int t = threadIdx.x, b = blockIdx.x;
    if (b < 8) {
        #pragma unroll
        for (int i = 0; i < 8; ++i) {
            int idx = b * 2048 + i * 256 + t;       // g*128+f
            int g = idx >> 7;
            w2h[idx ^ ((g & 7) << 3)] = (_Float16)W2[idx];
        }
    } else {
        int q = b - 8;
        #pragma unroll
        for (int i = 0; i < 8; ++i) {
            int idx = q * 2048 + i * 256 + t;       // f*128+c
            int f = idx >> 7, c = idx & 127;
            w1h[idx ^ ((f & 7) << 3)] = (_Float16)W1[f * CAT + 1 + c];
        }
        if (q == 0 && t < 128) w10h[t] = (_Float16)W1[t * CAT];
    }
}

// ---------------------------------------------------------------------------
// k_prep2: v1 = b1 + feature @ W1[:,1:]^T  (f16 MFMA GEMM, 16 rows/block),
// output stored as f16.
// ---------------------------------------------------------------------------
__global__ void __launch_bounds__(256) k_prep2(
    const float* __restrict__ feature, const _Float16* __restrict__ w1h,
    const float* __restrict__ b1p, _Float16* __restrict__ v1h)
{
    __shared__ __align__(16) _Float16 fS[2048];   // 16 x 128 f16, swizzled
    const int t = threadIdx.x;
    const int r0 = blockIdx.x * 16;

    {
        int e = t * 8;
        int r = e >> 7, c = e & 127;
        const float4* src = (const float4*)(feature + (size_t)(r0 + r) * 128 + c);
        float4 x0 = src[0], x1 = src[1];
        f16x8 hv;
        hv[0] = (_Float16)x0.x; hv[1] = (_Float16)x0.y;
        hv[2] = (_Float16)x0.z; hv[3] = (_Float16)x0.w;
        hv[4] = (_Float16)x1.x; hv[5] = (_Float16)x1.y;
        hv[6] = (_Float16)x1.z; hv[7] = (_Float16)x1.w;
        *(f16x8*)&fS[e ^ ((r & 7) << 3)] = hv;
    }
    __syncthreads();

    const int lane = t & 63, wv = t >> 6;
    const int l15 = lane & 15, l4 = lane >> 4;

    f16x8 bfr[2][4];
    float4 b1v[2];
    #pragma unroll
    for (int nt = 0; nt < 2; ++nt) {
        const int f0 = wv * 32 + nt * 16;
        b1v[nt] = *(const float4*)(b1p + f0 + l4 * 4);
        #pragma unroll
        for (int kc = 0; kc < 4; ++kc) {
            int f = f0 + l15, c = kc * 32 + l4 * 8;
            bfr[nt][kc] = *(const f16x8*)&w1h[(f * 128 + c) ^ ((f & 7) << 3)];
        }
    }

    const f32x4 fz = {0.f, 0.f, 0.f, 0.f};
    f32x4 acc[2] = {fz, fz};
    #pragma unroll
    for (int kc = 0; kc < 4; ++kc) {
        int r = l15, c = kc * 32 + l4 * 8;
        f16x8 afr = *(const f16x8*)&fS[(r * 128 + c) ^ ((r & 7) << 3)];
        #pragma unroll
        for (int nt = 0; nt < 2; ++nt)
            acc[nt] = __builtin_amdgcn_mfma_f32_16x16x32_f16(
                bfr[nt][kc], afr, acc[nt], 0, 0, 0);
    }

    #pragma unroll
    for (int nt = 0; nt < 2; ++nt) {
        f16x4 o;
        o[0] = (_Float16)(acc[nt][0] + ((const float*)&b1v[nt])[0]);
        o[1] = (_Float16)(acc[nt][1] + ((const float*)&b1v[nt])[1]);
        o[2] = (_Float16)(acc[nt][2] + ((const float*)&b1v[nt])[2]);
        o[3] = (_Float16)(acc[nt][3] + ((const float*)&b1v[nt])[3]);
        *(f16x4*)&v1h[(size_t)(r0 + l15) * 128 + wv * 32 + nt * 16 + l4 * 4] = o;
    }
}

// ---------------------------------------------------------------------------
// k_main: 2 bt per block, 512 threads = 8 waves (2 rg x 4 cg). All-f16
// datapath. Per 64-row quarter: packed-f16 h1 -> swizzled f16 LDS (double-
// buffered) -> MFMA D[g,r] (W2 frags in regs, b2 pre-folded into acc init) ->
// packed epilogue (cvt_pkrtz + pk prelu + fdot2) -> shfl reduce -> prs.
// One barrier per quarter; final/store runs on a rotating wave, overlapped.
// ---------------------------------------------------------------------------
__global__ void __launch_bounds__(512, 4) k_main(
    const float* __restrict__ inp, const float* __restrict__ b2p,
    const float* __restrict__ Wp, const float* __restrict__ bpp,
    const float* __restrict__ a1p, const float* __restrict__ a2p,
    const _Float16* __restrict__ v1h, const _Float16* __restrict__ w2h,
    const _Float16* __restrict__ w10h, float* __restrict__ out)
{
    __shared__ __align__(16) _Float16 h1s[16384];   // 2 x (64x128) bufs, 32 KB
    __shared__ float2 prs[2][4][64];                // double-buffered, 4 KB
    __shared__ float inps[512];                     // 2 bt rows of input
    __shared__ _Float16 v1s[256];
    __shared__ _Float16 w10s[128];

    const int tid  = threadIdx.x;
    const int lane = tid & 63, wv = tid >> 6;
    const int rg   = wv >> 2, cg = wv & 3;
    const int l15  = lane & 15, l4 = lane >> 4;
    const int bt0  = blockIdx.x * 2;

    // ---- stage: W2 into h1s region (coalesced), inps, v1, w10 ----
    #pragma unroll
    for (int q = 0; q < 4; ++q)
        ((int4*)h1s)[q * 512 + tid] = ((const int4*)w2h)[q * 512 + tid];
    inps[tid] = inp[(size_t)bt0 * DD + tid];
    if (tid < 128)
        ((unsigned*)v1s)[tid] = ((const unsigned*)(v1h + (size_t)bt0 * 128))[tid];
    else if (tid < 192)
        ((unsigned*)w10s)[tid - 128] = ((const unsigned*)w10h)[tid - 128];

    // ---- scalars & per-thread constants ----
    h2 z2; z2[0] = (_Float16)0.f; z2[1] = (_Float16)0.f;
    h2 a1v, a2v;
    { _Float16 x = (_Float16)a1p[0]; a1v[0] = x; a1v[1] = x; }
    { _Float16 x = (_Float16)a2p[0]; a2v[0] = x; a2v[1] = x; }
    const float wpi0 = Wp[128], wpi1 = Wp[CAT + 128];
    const float bp0  = bpp[0],  bp1  = bpp[1];

    f32x4 accInit[2];
    h2 wpa_pk[2][2], wpb_pk[2][2];
    #pragma unroll
    for (int nt = 0; nt < 2; ++nt) {
        const int g0 = cg * 32 + nt * 16 + l4 * 4;
        accInit[nt][0] = b2p[g0];     accInit[nt][1] = b2p[g0 + 1];
        accInit[nt][2] = b2p[g0 + 2]; accInit[nt][3] = b2p[g0 + 3];
        wpa_pk[nt][0] = cvt_pk(Wp[g0],           Wp[g0 + 1]);
        wpa_pk[nt][1] = cvt_pk(Wp[g0 + 2],       Wp[g0 + 3]);
        wpb_pk[nt][0] = cvt_pk(Wp[CAT + g0],     Wp[CAT + g0 + 1]);
        wpb_pk[nt][1] = cvt_pk(Wp[CAT + g0 + 2], Wp[CAT + g0 + 3]);
    }
    __syncthreads();   // staged LDS visible

    // ---- W2 B-frags from the staged (pre-swizzled) tile in h1s ----
    f16x8 bfr[2][4];
    #pragma unroll
    for (int nt = 0; nt < 2; ++nt) {
        const int g = cg * 32 + nt * 16 + l15;
        #pragma unroll
        for (int kc = 0; kc < 4; ++kc)
            bfr[nt][kc] = *(const f16x8*)
                &h1s[(g * 128 + kc * 32 + l4 * 8) ^ ((g & 7) << 3)];
    }

    // ---- h1-gen mapping + hoisted regs + precomputed LDS offsets ----
    const int lr = tid >> 3, fg = tid & 7;
    h2 w10pk[8];
    #pragma unroll
    for (int m = 0; m < 8; ++m)
        w10pk[m] = *(const h2*)&w10s[fg * 16 + m * 2];

    int roff[2][4];
    #pragma unroll
    for (int rt = 0; rt < 2; ++rt) {
        const int R = rg * 32 + rt * 16 + l15;
        #pragma unroll
        for (int kc = 0; kc < 4; ++kc)
            roff[rt][kc] = (R * 128 + kc * 32 + l4 * 8) ^ ((R & 7) << 3);
    }
    const int woffA = (lr * 128 + fg * 16)     ^ ((lr & 7) << 3);
    const int woffB = (lr * 128 + fg * 16 + 8) ^ ((lr & 7) << 3);

    h2 v1pk[8];
    __syncthreads();   // all bfr reads done before h1 writes overwrite W2

    #pragma unroll 2
    for (int i = 0; i < 8; ++i) {
        const int btl = i >> 2, qt = i & 3, buf = i & 1;
        if (i == 0 || i == 4) {
            #pragma unroll
            for (int m = 0; m < 8; ++m)
                v1pk[m] = *(const h2*)&v1s[btl * 128 + fg * 16 + m * 2];
        }

        // ---- h1 tile: 64 rows x 128 f, packed f16 ----
        {
            const float s = inps[btl * 256 + qt * 64 + lr];
            h2 s2; { _Float16 sh = (_Float16)s; s2[0] = sh; s2[1] = sh; }
            f16x8 w0, w1;
            #pragma unroll
            for (int m = 0; m < 8; ++m) {
                h2 h  = v1pk[m] + w10pk[m] * s2;
                h2 hp = __builtin_elementwise_max(h, z2)
                      + a1v * __builtin_elementwise_min(h, z2);
                if (m < 4) { w0[2 * m] = hp[0]; w0[2 * m + 1] = hp[1]; }
                else { w1[2 * (m - 4)] = hp[0]; w1[2 * (m - 4) + 1] = hp[1]; }
            }
            *(f16x8*)&h1s[buf * 8192 + woffA] = w0;
            *(f16x8*)&h1s[buf * 8192 + woffB] = w1;
        }
        __syncthreads();

        // ---- previous quarter's final on a rotating wave (overlapped) ----
        if (i > 0 && wv == (i - 1)) {
            const int pb = (i - 1) & 1, pbt = (i - 1) >> 2, pq = (i - 1) & 3;
            const float s = inps[pbt * 256 + pq * 64 + lane];
            const float2 t0 = prs[pb][0][lane], t1 = prs[pb][1][lane];
            const float2 t2 = prs[pb][2][lane], t3 = prs[pb][3][lane];
            const float e0 = t0.x + t1.x + t2.x + t3.x + wpi0 * s + bp0;
            const float e1 = t0.y + t1.y + t2.y + t3.y + wpi1 * s + bp1;
            const float gg = e0 / (1.f + __expf(-e1));
            out[(size_t)(bt0 + pbt) * DD + pq * 64 + lane] = s * (1.f + gg);
        }

        // ---- MFMA: D[g, r]; b2 pre-folded via accInit ----
        f32x4 acc[2][2];
        #pragma unroll
        for (int nt = 0; nt < 2; ++nt) {
            acc[nt][0] = accInit[nt];
            acc[nt][1] = accInit[nt];
        }
        #pragma unroll
        for (int kc = 0; kc < 4; ++kc) {
            f16x8 afr[2];
            #pragma unroll
            for (int rt = 0; rt < 2; ++rt)
                afr[rt] = *(const f16x8*)&h1s[buf * 8192 + roff[rt][kc]];
            #pragma unroll
            for (int nt = 0; nt < 2; ++nt)
                #pragma unroll
                for (int rt = 0; rt < 2; ++rt)
                    acc[nt][rt] = __builtin_amdgcn_mfma_f32_16x16x32_f16(
                        bfr[nt][kc], afr[rt], acc[nt][rt], 0, 0, 0);
        }

        // ---- packed epilogue: prelu(a2) + Wp dots + shfl reduce ----
        #pragma unroll
        for (int rt = 0; rt < 2; ++rt) {
            float s0 = 0.f, s1 = 0.f;
            #pragma unroll
            for (int nt = 0; nt < 2; ++nt)
                #pragma unroll
                for (int p = 0; p < 2; ++p) {
                    h2 hh = cvt_pk(acc[nt][rt][2 * p], acc[nt][rt][2 * p + 1]);
                    h2 hp = __builtin_elementwise_max(hh, z2)
                          + a2v * __builtin_elementwise_min(hh, z2);
                    s0 = fdot2f(wpa_pk[nt][p], hp, s0);
                    s1 = fdot2f(wpb_pk[nt][p], hp, s1);
                }
            s0 += __shfl_xor(s0, 16); s0 += __shfl_xor(s0, 32);
            s1 += __shfl_xor(s1, 16); s1 += __shfl_xor(s1, 32);
            if (l4 == 0) {
                float2 v; v.x = s0; v.y = s1;
                prs[buf][cg][rg * 32 + rt * 16 + l15] = v;
            }
        }
    }

    __syncthreads();
    if (wv == 7) {   // final for quarter 7
        const float s = inps[256 + 192 + lane];
        const float2 t0 = prs[1][0][lane], t1 = prs[1][1][lane];
        const float2 t2 = prs[1][2][lane], t3 = prs[1][3][lane];
        const float e0 = t0.x + t1.x + t2.x + t3.x + wpi0 * s + bp0;
        const float e1 = t0.y + t1.y + t2.y + t3.y + wpi1 * s + bp1;
        const float gg = e0 / (1.f + __expf(-e1));
        out[(size_t)(bt0 + 1) * DD + 192 + lane] = s * (1.f + gg);
    }
}

// ---------------------------------------------------------------------------
extern "C" void kernel_launch(void* const* d_in, const int* in_sizes, int n_in,
                              void* d_out, int out_size, void* d_ws, size_t ws_size,
                              hipStream_t stream)
{
    (void)in_sizes; (void)n_in; (void)out_size; (void)ws_size;
    const float* input   = (const float*)d_in[0];
    const float* feature = (const float*)d_in[1];
    // d_in[2] slider: unused by the reference computation
    const float* W1 = (const float*)d_in[3];
    const float* b1 = (const float*)d_in[4];
    const float* a1 = (const float*)d_in[5];
    const float* W2 = (const float*)d_in[6];
    const float* b2 = (const float*)d_in[7];
    const float* a2 = (const float*)d_in[8];
    const float* Wp = (const float*)d_in[9];
    const float* bp = (const float*)d_in[10];
    float* out = (float*)d_out;

    // workspace: v1h 1MB | w2h 32KB | w1h 32KB | w10h 256B
    _Float16* v1h  = (_Float16*)d_ws;
    _Float16* w2h  = v1h + (size_t)BT * 128;
    _Float16* w1h  = w2h + 16384;
    _Float16* w10h = w1h + 16384;

    k_cvt  <<<dim3(16),   dim3(256), 0, stream>>>(W1, W2, w2h, w1h, w10h);
    k_prep2<<<dim3(256),  dim3(256), 0, stream>>>(feature, w1h, b1, v1h);
    k_main <<<dim3(2048), dim3(512), 0, stream>>>(input, b2, Wp, bp, a1, a2,
                                                  v1h, w2h, w10h, out);
}